// Round 24
// baseline (217.859 us; speedup 1.0000x reference)
//
#include <hip/hip_runtime.h>
#include <math.h>

// DCGRU cell, N=8192, B=1, D_IN=2, UNITS=64, K=2 -> F=66, M=3.
// adj_mx @ v == adj^T @ (dinv*v) + (dinv*v)   (adj2 = adj + I folded in)
// R24: 5 launches: k_convb (R23: conv+dinv+build, 256x1024) -> hop1 -> hop2g
// -> hop1 -> hop2f. Hops now use gemm_core2 (R21-proven): TWO mt per block
// share B-fragment loads -> B L2-traffic halves (320->160 MB/hop), targeting
// the measured in-kernel hop cost (16.3us, ~9us of which is B at L2 BW).
// Grid 256 x 512thr. fp8 e4m3 superfrag GEMM, HW cvt packing, bf16 X0/X1.

typedef __attribute__((ext_vector_type(4))) float f32x4;
typedef __attribute__((ext_vector_type(2))) int v2i;
typedef __attribute__((ext_vector_type(4))) int v4i;
typedef unsigned char uch;
typedef unsigned short ush;

constexpr int NN  = 8192;
constexpr int CST = 80;
constexpr int KBT = 256;                     // k-blocks of 32
constexpr int SFT = KBT / 2;                 // 128 superfrags per mt
constexpr size_t NS    = (size_t)NN * CST;
constexpr size_t UTFS8 = (size_t)SFT * 5 * 1024;

constexpr float SC1  = 4096.f,   ISC1 = 1.f / 4096.f;     // hop1 B scale (2^12)
constexpr float SC2  = 262144.f, ISC2 = 1.f / 262144.f;   // hop2 B scale (2^18)

static __device__ __forceinline__ float bf2f(ush u) {
  union { float f; unsigned v; } c; c.v = ((unsigned)u) << 16; return c.f;
}
static __device__ __forceinline__ ush f2bf(float x) {
  union { float f; unsigned u; } c; c.f = x;
  unsigned u = c.u;
  u += 0x7fffu + ((u >> 16) & 1u);           // RNE
  return (ush)(u >> 16);
}

static __device__ __forceinline__ unsigned cvt2_fp8(float a, float b) {
  unsigned r = 0;
  asm("v_cvt_pk_fp8_f32 %0, %1, %2" : "+v"(r) : "v"(a), "v"(b));
  return r;
}
static __device__ __forceinline__ uint2 pack8_fp8(const float* tv) {
  uint2 pk;
  pk.x = cvt2_fp8(tv[0], tv[1]) | (cvt2_fp8(tv[2], tv[3]) << 16);
  pk.y = cvt2_fp8(tv[4], tv[5]) | (cvt2_fp8(tv[6], tv[7]) << 16);
  return pk;
}

static __device__ __forceinline__ void mfma_f8(f32x4& acc, v2i a, v2i b) {
  asm("v_mfma_f32_16x16x32_fp8_fp8 %0, %1, %2, %0" : "+v"(acc) : "v"(a), "v"(b));
}
static __device__ __forceinline__ v2i lo2(v4i v) { v2i r; r.x = v.x; r.y = v.y; return r; }
static __device__ __forceinline__ v2i hi2(v4i v) { v2i r; r.x = v.z; r.y = v.w; return r; }

// -------- fused: adj->fp8 superfrags + full row sums + dinv + build tail -----
__global__ __launch_bounds__(1024, 1) void k_convb(const float* __restrict__ adj,
                                                   const float* __restrict__ hx,
                                                   const float* __restrict__ inp,
                                                   uch* __restrict__ adjF8,
                                                   float* __restrict__ dinv,
                                                   ush* __restrict__ X0b,
                                                   uch* __restrict__ UtF8) {
  __shared__ __align__(16) float tile[4][2][32][132];   // 132 KB
  __shared__ float sums[4][32];
  __shared__ float dv_s[32];
  const int kb = blockIdx.x;
  const int tid = threadIdx.x;
  const int q = tid >> 8, qtid = tid & 255;
  const int l = qtid & 63, w = qtid >> 6;
  const int rg = qtid >> 5;
  const int cb = (qtid & 31) * 4;
  const int n0 = kb * 32;
  float rs[4] = {0.f, 0.f, 0.f, 0.f};

  {
    const int mc = q;
    const float* src = adj + ((size_t)kb * 32 + rg) * NN + (size_t)mc * 2048 + cb;
    float4 vA[4], vB[4];
#pragma unroll
    for (int i = 0; i < 4; ++i)
      vA[i] = *(const float4*)(src + (size_t)(8 * i) * NN);

#define CONV_BODY(CH, BUF, VC, VN)                                             \
    {                                                                          \
      const int ch_ = (CH);                                                    \
      _Pragma("unroll") for (int i = 0; i < 4; ++i) {                          \
        int r = rg + 8 * i;                                                    \
        int colp = (cb + 8 * i) & 127;                                         \
        *(float4*)&tile[q][BUF][r][colp] = VC[i];                              \
        rs[i] += (VC[i].x + VC[i].y) + (VC[i].z + VC[i].w);                    \
      }                                                                        \
      if (ch_ < 15) {                                                          \
        _Pragma("unroll") for (int i = 0; i < 4; ++i)                          \
            VN[i] = *(const float4*)(src + (size_t)(8 * i) * NN + (ch_ + 1) * 128); \
      }                                                                        \
      __syncthreads();                                                         \
      _Pragma("unroll") for (int hh = 0; hh < 2; ++hh) {                       \
        int fl = w + 4 * hh;                                                   \
        int mt = mc * 128 + ch_ * 8 + fl;                                      \
        int colp = (fl * 16 + (l & 15) + 8 * (l >> 4)) & 127;                  \
        float tv[8];                                                           \
        _Pragma("unroll") for (int j = 0; j < 8; ++j)                          \
          tv[j] = tile[q][BUF][8 * (l >> 4) + j][colp];                        \
        uint2 pk = pack8_fp8(tv);                                              \
        *(uint2*)(adjF8 + ((size_t)mt * SFT + (kb >> 1)) * 1024                \
                  + l * 16 + (kb & 1) * 8) = pk;                               \
      }                                                                        \
    }

    for (int cp = 0; cp < 8; ++cp) {
      CONV_BODY(2 * cp,     0, vA, vB);
      CONV_BODY(2 * cp + 1, 1, vB, vA);
    }
#undef CONV_BODY
  }

#pragma unroll
  for (int i = 0; i < 4; ++i) {
#pragma unroll
    for (int m = 16; m >= 1; m >>= 1) rs[i] += __shfl_xor(rs[i], m);
  }
  if ((qtid & 31) == 0) {
#pragma unroll
    for (int i = 0; i < 4; ++i) sums[q][8 * i + rg] = rs[i];
  }
  __syncthreads();
  if (tid < 32) {
    float dv = 1.f / (sums[0][tid] + sums[1][tid] + sums[2][tid] +
                      sums[3][tid] + 1.f);
    dv_s[tid] = dv;
    dinv[n0 + tid] = dv;
  }
  __syncthreads();

  for (int p = tid; p < 32 * 20; p += 1024) {
    int nl = p / 20, c4 = (p % 20) * 4;
    int n = n0 + nl;
    float v[4];
#pragma unroll
    for (int j = 0; j < 4; ++j) {
      int c = c4 + j;
      v[j] = (c < 64) ? hx[n * 64 + c] : (c < 66 ? inp[n * 2 + (c - 64)] : 0.f);
    }
    uint2 pk;
    pk.x = f2bf(v[0]) | ((unsigned)f2bf(v[1]) << 16);
    pk.y = f2bf(v[2]) | ((unsigned)f2bf(v[3]) << 16);
    *(uint2*)(X0b + (size_t)n * CST + c4) = pk;
  }
  if (tid < 5 * 64) {
    int nt = tid >> 6, l2 = tid & 63;
    float tv[8];
#pragma unroll
    for (int j = 0; j < 8; ++j) {
      int lr = 8 * (l2 >> 4) + j;
      int n = n0 + lr;
      int c = nt * 16 + (l2 & 15);
      float v = (c < 64) ? hx[n * 64 + c] : (c < 66 ? inp[n * 2 + (c - 64)] : 0.f);
      tv[j] = v * dv_s[lr] * SC1;
    }
    uint2 pk = pack8_fp8(tv);
    *(uint2*)(UtF8 + ((size_t)(kb >> 1) * 5 + nt) * 1024 + l2 * 16 + (kb & 1) * 8) = pk;
  }
}

// ---------------- GEMM core: fp8, TWO mt per block, shared B (R21-proven) ----
// Block bid owns mt = 2*bid, 2*bid+1 (nodes bid*32..+31). Wave w8: 16 sf.
// sv[i] = dot * inv_scale for item p = tid + i*512 of the 32x80 tile.
static __device__ __forceinline__ void gemm_core2(const uch* __restrict__ adjF8,
                                                  const uch* __restrict__ bF8,
                                                  int bid, int tid, float* smem,
                                                  float sv[5], float inv_scale) {
  const int w8 = tid >> 6, l = tid & 63;
  const int sf0 = w8 * 16;
  f32x4 acc0[5], acc1[5];
#pragma unroll
  for (int nt = 0; nt < 5; ++nt) {
    acc0[nt] = (f32x4){0.f, 0.f, 0.f, 0.f};
    acc1[nt] = (f32x4){0.f, 0.f, 0.f, 0.f};
  }
  const size_t MSTR = (size_t)SFT * 1024;
  const uch* ap = adjF8 + ((size_t)(2 * bid) * SFT + sf0) * 1024 + l * 16;
  const uch* bp = bF8 + (size_t)sf0 * 5 * 1024 + l * 16;

  v4i A0e, A1e, A0o, A1o, Be[5], Bo[5];
  A0e = *(const v4i*)(ap);
  A1e = *(const v4i*)(ap + MSTR);
#pragma unroll
  for (int nt = 0; nt < 5; ++nt) Be[nt] = *(const v4i*)(bp + nt * 1024);

  for (int sf = 0; sf < 16; sf += 2) {
    A0o = *(const v4i*)(ap + (size_t)(sf + 1) * 1024);
    A1o = *(const v4i*)(ap + MSTR + (size_t)(sf + 1) * 1024);
#pragma unroll
    for (int nt = 0; nt < 5; ++nt)
      Bo[nt] = *(const v4i*)(bp + (size_t)((sf + 1) * 5 + nt) * 1024);
#pragma unroll
    for (int nt = 0; nt < 5; ++nt) {
      mfma_f8(acc0[nt], lo2(A0e), lo2(Be[nt]));
      mfma_f8(acc1[nt], lo2(A1e), lo2(Be[nt]));
    }
#pragma unroll
    for (int nt = 0; nt < 5; ++nt) {
      mfma_f8(acc0[nt], hi2(A0e), hi2(Be[nt]));
      mfma_f8(acc1[nt], hi2(A1e), hi2(Be[nt]));
    }
    A0e = *(const v4i*)(ap + (size_t)(sf + 2) * 1024);
    A1e = *(const v4i*)(ap + MSTR + (size_t)(sf + 2) * 1024);
#pragma unroll
    for (int nt = 0; nt < 5; ++nt)
      Be[nt] = *(const v4i*)(bp + (size_t)((sf + 2) * 5 + nt) * 1024);
#pragma unroll
    for (int nt = 0; nt < 5; ++nt) {
      mfma_f8(acc0[nt], lo2(A0o), lo2(Bo[nt]));
      mfma_f8(acc1[nt], lo2(A1o), lo2(Bo[nt]));
    }
#pragma unroll
    for (int nt = 0; nt < 5; ++nt) {
      mfma_f8(acc0[nt], hi2(A0o), hi2(Bo[nt]));
      mfma_f8(acc1[nt], hi2(A1o), hi2(Bo[nt]));
    }
  }
  asm volatile("s_nop 7\n\ts_nop 7\n\ts_nop 7" ::: "memory");

  auto red = reinterpret_cast<float(*)[64][40]>(smem);    // [4][64][40] = 40 KB
  if (w8 < 4) {
#pragma unroll
    for (int nt = 0; nt < 5; ++nt) {
      *(f32x4*)&red[w8][l][nt * 4]      = acc0[nt];
      *(f32x4*)&red[w8][l][20 + nt * 4] = acc1[nt];
    }
  }
  __syncthreads();
  if (w8 >= 4) {
#pragma unroll
    for (int nt = 0; nt < 5; ++nt) {
      f32x4 t0 = *(f32x4*)&red[w8 - 4][l][nt * 4];
      f32x4 t1 = *(f32x4*)&red[w8 - 4][l][20 + nt * 4];
      *(f32x4*)&red[w8 - 4][l][nt * 4]      = t0 + acc0[nt];
      *(f32x4*)&red[w8 - 4][l][20 + nt * 4] = t1 + acc1[nt];
    }
  }
  __syncthreads();
#pragma unroll
  for (int i = 0; i < 5; ++i) {
    int p = tid + i * 512;
    int r = p / 80, c = p % 80;
    int mtl = r >> 4, rl = r & 15;
    int ll = ((rl >> 2) << 4) | (c & 15);
    int slot = mtl * 20 + (((c >> 4) << 2) | (rl & 3));
    sv[i] = (((red[0][ll][slot] + red[1][ll][slot]) +
              red[2][ll][slot]) + red[3][ll][slot]) * inv_scale;
  }
  __syncthreads();                                        // smem reusable
}

// ---------------- hop1: X1 = A^T@(dinv*X0) + dinv*X0 ; X1b ; UtFout ----------
__global__ __launch_bounds__(512, 2) void k_hop1(const uch* __restrict__ adjF8,
                                                 const uch* __restrict__ UtFin,
                                                 const ush* __restrict__ X0b,
                                                 const float* __restrict__ dinv,
                                                 ush* __restrict__ X1b,
                                                 uch* __restrict__ UtFout) {
  __shared__ __align__(16) float smem[10240];
  const int b = blockIdx.x, tid = threadIdx.x;
  const int n0 = b * 32;
  float sv[5];
  gemm_core2(adjF8, UtFin, b, tid, smem, sv, ISC1);

  auto xs = reinterpret_cast<float(*)[80]>(smem);
#pragma unroll
  for (int i = 0; i < 5; ++i) {
    int p = tid + i * 512;
    size_t o = (size_t)n0 * CST + p;
    float dv = dinv[n0 + p / 80];
    float x1 = dv * bf2f(X0b[o]) + sv[i];
    X1b[o] = f2bf(x1);
    xs[p / 80][p % 80] = dv * x1;
  }
  __syncthreads();
  for (int p = tid; p < 5 * 64; p += 512) {
    int nt = p >> 6, l = p & 63;
    float tv[8];
#pragma unroll
    for (int j = 0; j < 8; ++j)
      tv[j] = xs[8 * (l >> 4) + j][nt * 16 + (l & 15)] * SC2;
    uint2 pk = pack8_fp8(tv);
    *(uint2*)(UtFout + ((size_t)(b >> 1) * 5 + nt) * 1024 + l * 16 + (b & 1) * 8) = pk;
  }
}

// ---------------- hop2+gates: X2 in LDS; sigmoid matmul; X0b := rh -----------
__global__ __launch_bounds__(512, 2) void k_hop2g(const uch* __restrict__ adjF8,
    const uch* __restrict__ UtFb, const ush* __restrict__ X1b,
    ush* __restrict__ X0b,
    const float* __restrict__ w_ru, const float* __restrict__ b_ru,
    const float* __restrict__ hx, const float* __restrict__ inp,
    const float* __restrict__ dinv,
    uch* __restrict__ UtFa, float* __restrict__ UG) {
  __shared__ __align__(16) float smem[10240];
  const int b = blockIdx.x, tid = threadIdx.x;
  const int n0 = b * 32;
  float sv[5];
  gemm_core2(adjF8, UtFb, b, tid, smem, sv, ISC2);

  auto xr2 = reinterpret_cast<float(*)[80]>(smem);        // [32][80] = 2560 f
  float* xr01 = smem + 2560;                              // [2][32][68] = 4352 f
  float* rhq  = smem + 2560 + 4352;                       // [32][64] = 2048 f
#pragma unroll
  for (int i = 0; i < 5; ++i) {
    int p = tid + i * 512;
    size_t o = (size_t)n0 * CST + p;
    float dv = dinv[n0 + p / 80];
    xr2[p / 80][p % 80] = 2.f * (dv * bf2f(X1b[o]) + sv[i]) - bf2f(X0b[o]);
  }
  for (int p = tid; p < 32 * 17; p += 512) {
    int nl = p / 17, c4 = (p % 17) * 4;
    size_t o = (size_t)(n0 + nl) * CST + c4;
#pragma unroll
    for (int j = 0; j < 4; ++j) {
      xr01[nl * 68 + c4 + j]           = bf2f(X0b[o + j]);
      xr01[32 * 68 + nl * 68 + c4 + j] = bf2f(X1b[o + j]);
    }
  }
  __syncthreads();

  const int nl = tid >> 4, og = tid & 15, o0 = og * 8;
  float acc[8];
#pragma unroll
  for (int j = 0; j < 8; ++j) acc[j] = b_ru[o0 + j];
  for (int c = 0; c < 66; ++c) {
    int f = (c < 64) ? (c + 2) : (c - 64);
    const float* wr = w_ru + (size_t)(f * 3) * 128 + o0;
    float xv[3];
    xv[0] = xr01[nl * 68 + c];
    xv[1] = xr01[32 * 68 + nl * 68 + c];
    xv[2] = xr2[nl][c];
#pragma unroll
    for (int m = 0; m < 3; ++m) {
      float wl[8];
      *(float4*)(wl)     = *(const float4*)(wr + m * 128);
      *(float4*)(wl + 4) = *(const float4*)(wr + m * 128 + 4);
#pragma unroll
      for (int j = 0; j < 8; ++j) acc[j] += xv[m] * wl[j];
    }
  }
  const int n = n0 + nl;
  const float dv = dinv[n];
  if (og < 8) {
#pragma unroll
    for (int j = 0; j < 8; ++j) {
      int o = o0 + j;
      float r = 1.f / (1.f + expf(-acc[j]));
      float rh = r * hx[n * 64 + o];
      X0b[(size_t)n * CST + o] = f2bf(rh);
      rhq[nl * 64 + o] = dv * rh;
    }
  } else {
#pragma unroll
    for (int j = 0; j < 8; ++j)
      UG[n * 64 + (o0 - 64) + j] = 1.f / (1.f + expf(-acc[j]));
  }
  __syncthreads();
  for (int p = tid; p < 5 * 64; p += 512) {
    int nt = p >> 6, l = p & 63;
    float tv[8];
#pragma unroll
    for (int j = 0; j < 8; ++j) {
      int lr = 8 * (l >> 4) + j;
      int nn = n0 + lr;
      int cc = nt * 16 + (l & 15);
      float v;
      if (cc < 64)      v = rhq[lr * 64 + cc];
      else if (cc < 66) v = dinv[nn] * inp[nn * 2 + (cc - 64)];
      else              v = 0.f;
      tv[j] = v * SC1;
    }
    uint2 pk = pack8_fp8(tv);
    *(uint2*)(UtFa + ((size_t)(b >> 1) * 5 + nt) * 1024 + l * 16 + (b & 1) * 8) = pk;
  }
}

// ---------------- hop2+final: X2 in LDS; tanh matmul; output -----------------
__global__ __launch_bounds__(512, 2) void k_hop2f(const uch* __restrict__ adjF8,
    const uch* __restrict__ UtFb, const ush* __restrict__ X1b,
    const ush* __restrict__ X0b, const float* __restrict__ dinv,
    const float* __restrict__ w_c, const float* __restrict__ b_c,
    const float* __restrict__ hx, const float* __restrict__ UG,
    float* __restrict__ out) {
  __shared__ __align__(16) float smem[10240];
  const int b = blockIdx.x, tid = threadIdx.x;
  const int n0 = b * 32;
  float sv[5];
  gemm_core2(adjF8, UtFb, b, tid, smem, sv, ISC2);

  auto xr2 = reinterpret_cast<float(*)[80]>(smem);
  float* xr01 = smem + 2560;
#pragma unroll
  for (int i = 0; i < 5; ++i) {
    int p = tid + i * 512;
    size_t o = (size_t)n0 * CST + p;
    float dv = dinv[n0 + p / 80];
    xr2[p / 80][p % 80] = 2.f * (dv * bf2f(X1b[o]) + sv[i]) - bf2f(X0b[o]);
  }
  for (int p = tid; p < 32 * 17; p += 512) {
    int nl = p / 17, c4 = (p % 17) * 4;
    size_t o = (size_t)(n0 + nl) * CST + c4;
#pragma unroll
    for (int j = 0; j < 4; ++j) {
      xr01[nl * 68 + c4 + j]           = bf2f(X0b[o + j]);
      xr01[32 * 68 + nl * 68 + c4 + j] = bf2f(X1b[o + j]);
    }
  }
  __syncthreads();

  const int nl = tid >> 4, ot = tid & 15, o0 = ot * 4;
  float acc[4];
#pragma unroll
  for (int j = 0; j < 4; ++j) acc[j] = b_c[o0 + j];
  for (int c = 0; c < 66; ++c) {
    int f = (c < 64) ? (c + 2) : (c - 64);
    float xv[3];
    xv[0] = xr01[nl * 68 + c];
    xv[1] = xr01[32 * 68 + nl * 68 + c];
    xv[2] = xr2[nl][c];
#pragma unroll
    for (int m = 0; m < 3; ++m) {
      float wl[4];
      *(float4*)(wl) = *(const float4*)(w_c + (size_t)(f * 3 + m) * 64 + o0);
#pragma unroll
      for (int j = 0; j < 4; ++j) acc[j] += xv[m] * wl[j];
    }
  }
  const int n = n0 + nl;
#pragma unroll
  for (int j = 0; j < 4; ++j) {
    int o = o0 + j;
    float cc2 = tanhf(acc[j]);
    float u = UG[n * 64 + o];
    float h = hx[n * 64 + o];
    out[n * 64 + o] = u * h + (1.f - u) * cc2;
  }
}

// ---------------- launcher ----------------------------------------------------
extern "C" void kernel_launch(void* const* d_in, const int* in_sizes, int n_in,
                              void* d_out, int out_size, void* d_ws, size_t ws_size,
                              hipStream_t stream) {
  const float* inp  = (const float*)d_in[0];
  const float* hx   = (const float*)d_in[1];
  const float* adj  = (const float*)d_in[2];
  const float* w_ru = (const float*)d_in[3];
  const float* b_ru = (const float*)d_in[4];
  const float* w_c  = (const float*)d_in[5];
  const float* b_c  = (const float*)d_in[6];
  float* out = (float*)d_out;

  float* ws    = (float*)d_ws;
  float* dinv  = ws;                          // 8192 (pad to 16384)
  ush* X0b     = (ush*)(ws + 16384);          // NS ushorts
  ush* X1b     = X0b + NS;                    // NS ushorts
  uch* UtFa8   = (uch*)(X1b + NS);            // 640 KB
  uch* UtFb8   = UtFa8 + UTFS8;               // 640 KB
  uch* adjF8   = UtFb8 + UTFS8;               // 64 MB
  float* UG    = (float*)(adjF8 + (size_t)512 * SFT * 1024);  // [N][64] + OOB pad

  k_convb<<<256, 1024, 0, stream>>>(adj, hx, inp, adjF8, dinv, X0b, UtFa8);

  // gconv 1 (gates)
  k_hop1 <<<256, 512, 0, stream>>>(adjF8, UtFa8, X0b, dinv, X1b, UtFb8);
  k_hop2g<<<256, 512, 0, stream>>>(adjF8, UtFb8, X1b, X0b, w_ru, b_ru, hx, inp,
                                   dinv, UtFa8, UG);

  // gconv 2 (candidate)
  k_hop1 <<<256, 512, 0, stream>>>(adjF8, UtFa8, X0b, dinv, X1b, UtFb8);
  k_hop2f<<<256, 512, 0, stream>>>(adjF8, UtFb8, X1b, X0b, dinv, w_c, b_c, hx,
                                   UG, out);
}

// Round 25
// 206.647 us; speedup vs baseline: 1.0543x; 1.0543x over previous
//
#include <hip/hip_runtime.h>
#include <math.h>

// DCGRU cell, N=8192, B=1, D_IN=2, UNITS=64, K=2 -> F=66, M=3.
// adj_mx @ v == adj^T @ (dinv*v) + (dinv*v)   (adj2 = adj + I folded in)
// R25 = R23 verbatim (best: 207.5 us). 5 launches: k_convb (conv+dinv+build,
// 256 blk x 1024 thr, 16 waves/CU) -> hop1 -> hop2g -> hop1 -> hop2f.
// Hops: fp8 e4m3 superfrag GEMM (v_mfma_f32_16x16x32_fp8_fp8), one mt per
// block (512 blk x 512 thr, 2 blk/CU), HW v_cvt_pk_fp8_f32 packing, bf16
// X0/X1, dinv recomputed on the fly. R24's B-sharing regressed (occupancy
// loss > B-traffic gain) -> reverted.

typedef __attribute__((ext_vector_type(4))) float f32x4;
typedef __attribute__((ext_vector_type(2))) int v2i;
typedef __attribute__((ext_vector_type(4))) int v4i;
typedef unsigned char uch;
typedef unsigned short ush;

constexpr int NN  = 8192;
constexpr int CST = 80;
constexpr int KBT = 256;                     // k-blocks of 32
constexpr int SFT = KBT / 2;                 // 128 superfrags per mt
constexpr size_t NS    = (size_t)NN * CST;
constexpr size_t UTFS8 = (size_t)SFT * 5 * 1024;

constexpr float SC1  = 4096.f,   ISC1 = 1.f / 4096.f;     // hop1 B scale (2^12)
constexpr float SC2  = 262144.f, ISC2 = 1.f / 262144.f;   // hop2 B scale (2^18)

static __device__ __forceinline__ float bf2f(ush u) {
  union { float f; unsigned v; } c; c.v = ((unsigned)u) << 16; return c.f;
}
static __device__ __forceinline__ ush f2bf(float x) {
  union { float f; unsigned u; } c; c.f = x;
  unsigned u = c.u;
  u += 0x7fffu + ((u >> 16) & 1u);           // RNE
  return (ush)(u >> 16);
}

static __device__ __forceinline__ unsigned cvt2_fp8(float a, float b) {
  unsigned r = 0;
  asm("v_cvt_pk_fp8_f32 %0, %1, %2" : "+v"(r) : "v"(a), "v"(b));
  return r;
}
static __device__ __forceinline__ uint2 pack8_fp8(const float* tv) {
  uint2 pk;
  pk.x = cvt2_fp8(tv[0], tv[1]) | (cvt2_fp8(tv[2], tv[3]) << 16);
  pk.y = cvt2_fp8(tv[4], tv[5]) | (cvt2_fp8(tv[6], tv[7]) << 16);
  return pk;
}

static __device__ __forceinline__ void mfma_f8(f32x4& acc, v2i a, v2i b) {
  asm("v_mfma_f32_16x16x32_fp8_fp8 %0, %1, %2, %0" : "+v"(acc) : "v"(a), "v"(b));
}
static __device__ __forceinline__ v2i lo2(v4i v) { v2i r; r.x = v.x; r.y = v.y; return r; }
static __device__ __forceinline__ v2i hi2(v4i v) { v2i r; r.x = v.z; r.y = v.w; return r; }

// -------- fused: adj->fp8 superfrags + full row sums + dinv + build tail -----
// 256 blocks x 1024 thr. Block kb owns adj rows kb*32..+31 (= nodes n0..n0+31).
// Quarter q = tid>>8 processes column chunk mc = q (2048 cols); row sums
// combined 4-way in LDS -> dinv -> X0b/UtFa8 build tail.
__global__ __launch_bounds__(1024, 1) void k_convb(const float* __restrict__ adj,
                                                   const float* __restrict__ hx,
                                                   const float* __restrict__ inp,
                                                   uch* __restrict__ adjF8,
                                                   float* __restrict__ dinv,
                                                   ush* __restrict__ X0b,
                                                   uch* __restrict__ UtF8) {
  __shared__ __align__(16) float tile[4][2][32][132];   // 132 KB
  __shared__ float sums[4][32];
  __shared__ float dv_s[32];
  const int kb = blockIdx.x;
  const int tid = threadIdx.x;
  const int q = tid >> 8, qtid = tid & 255;
  const int l = qtid & 63, w = qtid >> 6;
  const int rg = qtid >> 5;
  const int cb = (qtid & 31) * 4;
  const int n0 = kb * 32;
  float rs[4] = {0.f, 0.f, 0.f, 0.f};

  {
    const int mc = q;
    const float* src = adj + ((size_t)kb * 32 + rg) * NN + (size_t)mc * 2048 + cb;
    float4 vA[4], vB[4];
#pragma unroll
    for (int i = 0; i < 4; ++i)
      vA[i] = *(const float4*)(src + (size_t)(8 * i) * NN);

#define CONV_BODY(CH, BUF, VC, VN)                                             \
    {                                                                          \
      const int ch_ = (CH);                                                    \
      _Pragma("unroll") for (int i = 0; i < 4; ++i) {                          \
        int r = rg + 8 * i;                                                    \
        int colp = (cb + 8 * i) & 127;                                         \
        *(float4*)&tile[q][BUF][r][colp] = VC[i];                              \
        rs[i] += (VC[i].x + VC[i].y) + (VC[i].z + VC[i].w);                    \
      }                                                                        \
      if (ch_ < 15) {                                                          \
        _Pragma("unroll") for (int i = 0; i < 4; ++i)                          \
            VN[i] = *(const float4*)(src + (size_t)(8 * i) * NN + (ch_ + 1) * 128); \
      }                                                                        \
      __syncthreads();                                                         \
      _Pragma("unroll") for (int hh = 0; hh < 2; ++hh) {                       \
        int fl = w + 4 * hh;                                                   \
        int mt = mc * 128 + ch_ * 8 + fl;                                      \
        int colp = (fl * 16 + (l & 15) + 8 * (l >> 4)) & 127;                  \
        float tv[8];                                                           \
        _Pragma("unroll") for (int j = 0; j < 8; ++j)                          \
          tv[j] = tile[q][BUF][8 * (l >> 4) + j][colp];                        \
        uint2 pk = pack8_fp8(tv);                                              \
        *(uint2*)(adjF8 + ((size_t)mt * SFT + (kb >> 1)) * 1024                \
                  + l * 16 + (kb & 1) * 8) = pk;                               \
      }                                                                        \
    }

    for (int cp = 0; cp < 8; ++cp) {
      CONV_BODY(2 * cp,     0, vA, vB);
      CONV_BODY(2 * cp + 1, 1, vB, vA);
    }
#undef CONV_BODY
  }

#pragma unroll
  for (int i = 0; i < 4; ++i) {
#pragma unroll
    for (int m = 16; m >= 1; m >>= 1) rs[i] += __shfl_xor(rs[i], m);
  }
  if ((qtid & 31) == 0) {
#pragma unroll
    for (int i = 0; i < 4; ++i) sums[q][8 * i + rg] = rs[i];
  }
  __syncthreads();
  if (tid < 32) {
    float dv = 1.f / (sums[0][tid] + sums[1][tid] + sums[2][tid] +
                      sums[3][tid] + 1.f);
    dv_s[tid] = dv;
    dinv[n0 + tid] = dv;
  }
  __syncthreads();

  // ---- build tail: X0b(bf16) + UtFa8 ----
  for (int p = tid; p < 32 * 20; p += 1024) {
    int nl = p / 20, c4 = (p % 20) * 4;
    int n = n0 + nl;
    float v[4];
#pragma unroll
    for (int j = 0; j < 4; ++j) {
      int c = c4 + j;
      v[j] = (c < 64) ? hx[n * 64 + c] : (c < 66 ? inp[n * 2 + (c - 64)] : 0.f);
    }
    uint2 pk;
    pk.x = f2bf(v[0]) | ((unsigned)f2bf(v[1]) << 16);
    pk.y = f2bf(v[2]) | ((unsigned)f2bf(v[3]) << 16);
    *(uint2*)(X0b + (size_t)n * CST + c4) = pk;
  }
  if (tid < 5 * 64) {
    int nt = tid >> 6, l2 = tid & 63;
    float tv[8];
#pragma unroll
    for (int j = 0; j < 8; ++j) {
      int lr = 8 * (l2 >> 4) + j;
      int n = n0 + lr;
      int c = nt * 16 + (l2 & 15);
      float v = (c < 64) ? hx[n * 64 + c] : (c < 66 ? inp[n * 2 + (c - 64)] : 0.f);
      tv[j] = v * dv_s[lr] * SC1;
    }
    uint2 pk = pack8_fp8(tv);
    *(uint2*)(UtF8 + ((size_t)(kb >> 1) * 5 + nt) * 1024 + l2 * 16 + (kb & 1) * 8) = pk;
  }
}

// ---------------- GEMM core: fp8, single mt, 8-wave K-split (16 sf each) -----
static __device__ __forceinline__ void gemm_core1(const uch* __restrict__ adjF8,
                                                  const uch* __restrict__ bF8,
                                                  int mt, int tid, float* smem,
                                                  float& sv0, float& sv1,
                                                  float& sv2, float inv_scale) {
  const int w8 = tid >> 6, l = tid & 63;
  const int sf0 = w8 * 16;
  f32x4 acc[5];
#pragma unroll
  for (int nt = 0; nt < 5; ++nt) acc[nt] = (f32x4){0.f, 0.f, 0.f, 0.f};
  const uch* ap = adjF8 + ((size_t)mt * SFT + sf0) * 1024 + l * 16;
  const uch* bp = bF8 + (size_t)sf0 * 5 * 1024 + l * 16;

  v4i Ae, Ao, Be[5], Bo[5];
  Ae = *(const v4i*)(ap);
#pragma unroll
  for (int nt = 0; nt < 5; ++nt) Be[nt] = *(const v4i*)(bp + nt * 1024);

  for (int sf = 0; sf < 16; sf += 2) {
    Ao = *(const v4i*)(ap + (size_t)(sf + 1) * 1024);
#pragma unroll
    for (int nt = 0; nt < 5; ++nt)
      Bo[nt] = *(const v4i*)(bp + (size_t)((sf + 1) * 5 + nt) * 1024);
#pragma unroll
    for (int nt = 0; nt < 5; ++nt) mfma_f8(acc[nt], lo2(Ae), lo2(Be[nt]));
#pragma unroll
    for (int nt = 0; nt < 5; ++nt) mfma_f8(acc[nt], hi2(Ae), hi2(Be[nt]));
    Ae = *(const v4i*)(ap + (size_t)(sf + 2) * 1024);
#pragma unroll
    for (int nt = 0; nt < 5; ++nt)
      Be[nt] = *(const v4i*)(bp + (size_t)((sf + 2) * 5 + nt) * 1024);
#pragma unroll
    for (int nt = 0; nt < 5; ++nt) mfma_f8(acc[nt], lo2(Ao), lo2(Bo[nt]));
#pragma unroll
    for (int nt = 0; nt < 5; ++nt) mfma_f8(acc[nt], hi2(Ao), hi2(Bo[nt]));
  }
  asm volatile("s_nop 7\n\ts_nop 7\n\ts_nop 7" ::: "memory");

  auto red = reinterpret_cast<float(*)[64][20]>(smem);    // [4][64][20] = 20 KB
  if (w8 < 4) {
#pragma unroll
    for (int nt = 0; nt < 5; ++nt) *(f32x4*)&red[w8][l][nt * 4] = acc[nt];
  }
  __syncthreads();
  if (w8 >= 4) {
#pragma unroll
    for (int nt = 0; nt < 5; ++nt) {
      f32x4 t = *(f32x4*)&red[w8 - 4][l][nt * 4];
      *(f32x4*)&red[w8 - 4][l][nt * 4] = t + acc[nt];
    }
  }
  __syncthreads();
#define GATHER(P)                                                              \
  ({ int p_ = (P); int r_ = p_ / 80, c_ = p_ % 80;                             \
     int ll_ = ((r_ >> 2) << 4) | (c_ & 15);                                   \
     int k_ = ((c_ >> 4) << 2) | (r_ & 3);                                     \
     (((red[0][ll_][k_] + red[1][ll_][k_]) + red[2][ll_][k_])                  \
      + red[3][ll_][k_]) * inv_scale; })
  sv0 = GATHER(tid);
  sv1 = GATHER(tid + 512);
  sv2 = (tid < 256) ? GATHER(tid + 1024) : 0.f;
#undef GATHER
  __syncthreads();                                        // smem reusable
}

// half-fragment UtF writer: block owns rows 16*(mt&1)..+15 of kb = mt>>1.
#define UTF_WRITE_HALF(DST, VALEXPR, SCALE)                                    \
  {                                                                            \
    const int sfK = mt >> 2;                                                   \
    const int byteoff = ((mt >> 1) & 1) * 8;                                   \
    const int lbase = (mt & 1) * 32;                                           \
    for (int p = tid; p < 5 * 32; p += 512) {                                  \
      int nt = p >> 5, idx = p & 31;                                           \
      int l2 = lbase + idx;                                                    \
      float tv_[8];                                                            \
      _Pragma("unroll") for (int j = 0; j < 8; ++j) {                          \
        int lr = 8 * (idx >> 4) + j;                                           \
        int cc = nt * 16 + (idx & 15);                                         \
        tv_[j] = (VALEXPR) * (SCALE);                                          \
      }                                                                        \
      uint2 pk = pack8_fp8(tv_);                                               \
      *(uint2*)((DST) + ((size_t)sfK * 5 + nt) * 1024 + l2 * 16 + byteoff) = pk; \
    }                                                                          \
  }

// ---------------- hop1: X1 = A^T@(dinv*X0) + dinv*X0 ; X1b ; UtFout ----------
__global__ __launch_bounds__(512, 4) void k_hop1(const uch* __restrict__ adjF8,
                                                 const uch* __restrict__ UtFin,
                                                 const ush* __restrict__ X0b,
                                                 const float* __restrict__ dinv,
                                                 ush* __restrict__ X1b,
                                                 uch* __restrict__ UtFout) {
  __shared__ __align__(16) float smem[5120];
  const int mt = blockIdx.x, tid = threadIdx.x;
  const int n0 = mt * 16;
  float sv0, sv1, sv2;
  gemm_core1(adjF8, UtFin, mt, tid, smem, sv0, sv1, sv2, ISC1);

  auto xs = reinterpret_cast<float(*)[80]>(smem);
#define HOP1_ITEM(P, SV)                                                       \
  { int p_ = (P); size_t o_ = (size_t)n0 * CST + p_;                           \
    float dv_ = dinv[n0 + p_ / 80];                                            \
    float x1_ = dv_ * bf2f(X0b[o_]) + (SV);                                    \
    X1b[o_] = f2bf(x1_);                                                       \
    xs[p_ / 80][p_ % 80] = dv_ * x1_; }
  HOP1_ITEM(tid, sv0)
  HOP1_ITEM(tid + 512, sv1)
  if (tid < 256) HOP1_ITEM(tid + 1024, sv2)
#undef HOP1_ITEM
  __syncthreads();
  UTF_WRITE_HALF(UtFout, xs[lr][cc], SC2)
}

// ---------------- hop2+gates: X2 in LDS; sigmoid matmul; X0b := rh -----------
__global__ __launch_bounds__(512, 4) void k_hop2g(const uch* __restrict__ adjF8,
    const uch* __restrict__ UtFb, const ush* __restrict__ X1b,
    ush* __restrict__ X0b,
    const float* __restrict__ w_ru, const float* __restrict__ b_ru,
    const float* __restrict__ hx, const float* __restrict__ inp,
    const float* __restrict__ dinv,
    uch* __restrict__ UtFa, float* __restrict__ UG) {
  __shared__ __align__(16) float smem[5120];
  const int mt = blockIdx.x, tid = threadIdx.x;
  const int n0 = mt * 16;
  float sv0, sv1, sv2;
  gemm_core1(adjF8, UtFb, mt, tid, smem, sv0, sv1, sv2, ISC2);

  auto xr2 = reinterpret_cast<float(*)[80]>(smem);        // [16][80] = 1280
  float* xr01 = smem + 1280;                              // [2][16][68] = 2176
  float* rhq  = smem + 1280 + 2176;                       // [16][64] = 1024
#define X2_ITEM(P, SV)                                                         \
  { int p_ = (P); size_t o_ = (size_t)n0 * CST + p_;                           \
    float dv_ = dinv[n0 + p_ / 80];                                            \
    xr2[p_ / 80][p_ % 80] =                                                    \
        2.f * (dv_ * bf2f(X1b[o_]) + (SV)) - bf2f(X0b[o_]); }
  X2_ITEM(tid, sv0)
  X2_ITEM(tid + 512, sv1)
  if (tid < 256) X2_ITEM(tid + 1024, sv2)
#undef X2_ITEM
  for (int p = tid; p < 16 * 17; p += 512) {
    int nl = p / 17, c4 = (p % 17) * 4;
    size_t o = (size_t)(n0 + nl) * CST + c4;
#pragma unroll
    for (int j = 0; j < 4; ++j) {
      xr01[nl * 68 + c4 + j]           = bf2f(X0b[o + j]);
      xr01[16 * 68 + nl * 68 + c4 + j] = bf2f(X1b[o + j]);
    }
  }
  __syncthreads();

  const int nl = tid >> 5, og = tid & 31, o0 = og * 4;
  float acc[4];
#pragma unroll
  for (int j = 0; j < 4; ++j) acc[j] = b_ru[o0 + j];
  for (int c = 0; c < 66; ++c) {
    int f = (c < 64) ? (c + 2) : (c - 64);
    const float* wr = w_ru + (size_t)(f * 3) * 128 + o0;
    float xv[3];
    xv[0] = xr01[nl * 68 + c];
    xv[1] = xr01[16 * 68 + nl * 68 + c];
    xv[2] = xr2[nl][c];
#pragma unroll
    for (int m = 0; m < 3; ++m) {
      float wl[4];
      *(float4*)(wl) = *(const float4*)(wr + m * 128);
#pragma unroll
      for (int j = 0; j < 4; ++j) acc[j] += xv[m] * wl[j];
    }
  }
  const int n = n0 + nl;
  const float dv = dinv[n];
  if (og < 16) {
#pragma unroll
    for (int j = 0; j < 4; ++j) {
      int o = o0 + j;
      float r = 1.f / (1.f + expf(-acc[j]));
      float rh = r * hx[n * 64 + o];
      X0b[(size_t)n * CST + o] = f2bf(rh);
      rhq[nl * 64 + o] = dv * rh;
    }
  } else {
#pragma unroll
    for (int j = 0; j < 4; ++j)
      UG[n * 64 + (o0 - 64) + j] = 1.f / (1.f + expf(-acc[j]));
  }
  __syncthreads();
  UTF_WRITE_HALF(UtFa,
                 (cc < 64) ? rhq[lr * 64 + cc]
                           : ((cc < 66) ? dinv[n0 + lr] * inp[(n0 + lr) * 2 + (cc - 64)]
                                        : 0.f),
                 SC1)
}

// ---------------- hop2+final: X2 in LDS; tanh matmul; output -----------------
__global__ __launch_bounds__(512, 4) void k_hop2f2(const uch* __restrict__ adjF8,
    const uch* __restrict__ UtFb, const ush* __restrict__ X1b,
    const ush* __restrict__ X0b, const float* __restrict__ dinv,
    const float* __restrict__ w_c, const float* __restrict__ b_c,
    const float* __restrict__ hx, const float* __restrict__ UG,
    float* __restrict__ out) {
  __shared__ __align__(16) float smem[5120];
  const int mt = blockIdx.x, tid = threadIdx.x;
  const int n0 = mt * 16;
  float sv0, sv1, sv2;
  gemm_core1(adjF8, UtFb, mt, tid, smem, sv0, sv1, sv2, ISC2);

  auto xr2 = reinterpret_cast<float(*)[80]>(smem);        // [16][80]
  float* xr01 = smem + 1280;                              // [2][16][68]
#define X2_ITEM(P, SV)                                                         \
  { int p_ = (P); size_t o_ = (size_t)n0 * CST + p_;                           \
    float dv_ = dinv[n0 + p_ / 80];                                            \
    xr2[p_ / 80][p_ % 80] =                                                    \
        2.f * (dv_ * bf2f(X1b[o_]) + (SV)) - bf2f(X0b[o_]); }
  X2_ITEM(tid, sv0)
  X2_ITEM(tid + 512, sv1)
  if (tid < 256) X2_ITEM(tid + 1024, sv2)
#undef X2_ITEM
  for (int p = tid; p < 16 * 17; p += 512) {
    int nl = p / 17, c4 = (p % 17) * 4;
    size_t o = (size_t)(n0 + nl) * CST + c4;
#pragma unroll
    for (int j = 0; j < 4; ++j) {
      xr01[nl * 68 + c4 + j]           = bf2f(X0b[o + j]);
      xr01[16 * 68 + nl * 68 + c4 + j] = bf2f(X1b[o + j]);
    }
  }
  __syncthreads();

  const int nl = tid >> 5, ot = tid & 31, o0 = ot * 2;
  float acc[2];
#pragma unroll
  for (int j = 0; j < 2; ++j) acc[j] = b_c[o0 + j];
  for (int c = 0; c < 66; ++c) {
    int f = (c < 64) ? (c + 2) : (c - 64);
    float xv[3];
    xv[0] = xr01[nl * 68 + c];
    xv[1] = xr01[16 * 68 + nl * 68 + c];
    xv[2] = xr2[nl][c];
#pragma unroll
    for (int m = 0; m < 3; ++m) {
      float wl[2];
      *(float2*)(wl) = *(const float2*)(w_c + (size_t)(f * 3 + m) * 64 + o0);
#pragma unroll
      for (int j = 0; j < 2; ++j) acc[j] += xv[m] * wl[j];
    }
  }
  const int n = n0 + nl;
#pragma unroll
  for (int j = 0; j < 2; ++j) {
    int o = o0 + j;
    float cc = tanhf(acc[j]);
    float u = UG[n * 64 + o];
    float h = hx[n * 64 + o];
    out[n * 64 + o] = u * h + (1.f - u) * cc;
  }
}

// ---------------- launcher ----------------------------------------------------
extern "C" void kernel_launch(void* const* d_in, const int* in_sizes, int n_in,
                              void* d_out, int out_size, void* d_ws, size_t ws_size,
                              hipStream_t stream) {
  const float* inp  = (const float*)d_in[0];
  const float* hx   = (const float*)d_in[1];
  const float* adj  = (const float*)d_in[2];
  const float* w_ru = (const float*)d_in[3];
  const float* b_ru = (const float*)d_in[4];
  const float* w_c  = (const float*)d_in[5];
  const float* b_c  = (const float*)d_in[6];
  float* out = (float*)d_out;

  float* ws    = (float*)d_ws;
  float* dinv  = ws;                          // 8192 (pad to 16384)
  ush* X0b     = (ush*)(ws + 16384);          // NS ushorts
  ush* X1b     = X0b + NS;                    // NS ushorts
  uch* UtFa8   = (uch*)(X1b + NS);            // 640 KB
  uch* UtFb8   = UtFa8 + UTFS8;               // 640 KB
  uch* adjF8   = UtFb8 + UTFS8;               // 64 MB
  float* UG    = (float*)(adjF8 + (size_t)512 * SFT * 1024);  // [N][64] + OOB pad

  k_convb<<<256, 1024, 0, stream>>>(adj, hx, inp, adjF8, dinv, X0b, UtFa8);

  // gconv 1 (gates)
  k_hop1 <<<512, 512, 0, stream>>>(adjF8, UtFa8, X0b, dinv, X1b, UtFb8);
  k_hop2g<<<512, 512, 0, stream>>>(adjF8, UtFb8, X1b, X0b, w_ru, b_ru, hx, inp,
                                   dinv, UtFa8, UG);

  // gconv 2 (candidate)
  k_hop1 <<<512, 512, 0, stream>>>(adjF8, UtFa8, X0b, dinv, X1b, UtFb8);
  k_hop2f2<<<512, 512, 0, stream>>>(adjF8, UtFb8, X1b, X0b, dinv, w_c, b_c, hx,
                                    UG, out);
}